// Round 1
// baseline (1252.481 us; speedup 1.0000x reference)
//
#include <hip/hip_runtime.h>
#include <stdint.h>
#include <math.h>

#define S_LEN   65536
#define DM      1024
#define HD_     128
#define HID_    2048
#define SCALE_F 0.08838834764831845f

typedef float          f32x4  __attribute__((ext_vector_type(4)));
typedef short          bf16x8 __attribute__((ext_vector_type(8)));
typedef unsigned short u16;

__device__ __forceinline__ u16 f2bf(float f) {
  union { float f; uint32_t u; } v; v.f = f;
  uint32_t u = v.u;
  u += 0x7FFFu + ((u >> 16) & 1u);
  return (u16)(u >> 16);
}

__device__ __forceinline__ bf16x8 pack_bf8(const float* f) {
  union { bf16x8 v; u16 s[8]; } r;
#pragma unroll
  for (int i = 0; i < 8; ++i) r.s[i] = f2bf(f[i]);
  return r.v;
}

// ---------------- workspace layout (bytes) ----------------
#define WS_Q      0u          // 8192 f32
#define WS_QKA    32768u      // 65536 bf16 (fragment-linear)
#define WS_QBK    163840u     // 64 f32
#define WS_GMAX   164096u     // 64 f32
#define WS_LSUM   164352u     // 64 f32
#define WS_PLSUM  164608u     // 512 f32
#define WS_EW     167936u     // 65536 f32
#define WS_PMAX   430080u     // 65536 f32
#define WS_OATT   692224u     // 8192 f32
#define WS_O2     724992u     // 8192 f32
#define WS_H1     757760u     // 16384 f32
#define WS_LOGITS 1048576u    // 64*65536 f32 (dead after k_make_e)
#define WS_PEW    1048576u    // 128*64*1024 f32 (reuses logits region)
#define WS_E      34603008u   // 64*65536 bf16

// q[m,j] = bq[j] + sum_i latents[m,i] wq[i,j]
__global__ void k_proj_q(const float* __restrict__ lat, const float* __restrict__ wq,
                         const float* __restrict__ bq, float* __restrict__ q) {
  int tid = blockIdx.x * 256 + threadIdx.x;       // 8192
  int m = tid >> 10, j = tid & 1023;
  float acc = bq[j];
  const float* lm = lat + m * DM;
#pragma unroll 4
  for (int i = 0; i < DM; ++i) acc += lm[i] * wq[(size_t)i * DM + j];
  q[tid] = acc;
}

// qkfold[r,c] (bf16, fragment-linear layout) + qbk[r]
__global__ void k_fold_qk(const float* __restrict__ q, const float* __restrict__ wk,
                          const float* __restrict__ bk, u16* __restrict__ qka,
                          float* __restrict__ qbk) {
  int tid = blockIdx.x * 256 + threadIdx.x;       // 65536
  int r = tid >> 10, c = tid & 1023;
  int m = r >> 3, h = r & 7;
  const float* qrow = q + m * DM + h * HD_;
  const float* wrow = wk + (size_t)c * DM + h * HD_;
  float acc = 0.f;
#pragma unroll 4
  for (int d = 0; d < HD_; ++d) acc += qrow[d] * wrow[d];
  acc *= SCALE_F;
  int K0 = c >> 5, rb = r >> 4, hi = (c & 31) >> 3, e = c & 7, l16 = r & 15;
  int lane = hi * 16 + l16;
  qka[(((K0 * 4 + rb) * 64 + lane) << 3) + e] = f2bf(acc);
  if (c == 0) {
    float a2 = 0.f;
    for (int d = 0; d < HD_; ++d) a2 += qrow[d] * bk[h * HD_ + d];
    qbk[r] = a2 * SCALE_F;
  }
}

// logits[64, S] = qkfold @ H^T (+qbk), plus per-tile row max
__global__ __launch_bounds__(256, 4) void k_logits(
    const float* __restrict__ h, const u16* __restrict__ qka,
    const float* __restrict__ qbk, float* __restrict__ logits,
    float* __restrict__ pmax) {
  __shared__ __align__(16) u16 Abuf[2][2048];
  __shared__ float pmL[4 * 64];
  int t = threadIdx.x, wg = blockIdx.x;
  int w = t >> 6, l = t & 63;
  int g = l >> 4, l15 = l & 15;
  int scol = wg * 64 + w * 16 + l15;

  ((uint4*)Abuf[0])[t] = ((const uint4*)qka)[t];
  __syncthreads();

  f32x4 acc[4];
#pragma unroll
  for (int rb = 0; rb < 4; ++rb) acc[rb] = (f32x4){0.f, 0.f, 0.f, 0.f};

  for (int ks = 0; ks < 32; ++ks) {
    int buf = ks & 1;
    if (ks + 1 < 32)
      ((uint4*)Abuf[buf ^ 1])[t] = ((const uint4*)(qka + (size_t)(ks + 1) * 2048))[t];
    const float* hp = h + (size_t)scol * DM + ks * 32 + g * 8;
    float fb[8];
    f32x4 f0 = *(const f32x4*)hp;
    f32x4 f1 = *(const f32x4*)(hp + 4);
    fb[0]=f0[0]; fb[1]=f0[1]; fb[2]=f0[2]; fb[3]=f0[3];
    fb[4]=f1[0]; fb[5]=f1[1]; fb[6]=f1[2]; fb[7]=f1[3];
    bf16x8 bfr = pack_bf8(fb);
    const bf16x8* ap = (const bf16x8*)Abuf[buf];
#pragma unroll
    for (int rb = 0; rb < 4; ++rb) {
      bf16x8 af = ap[rb * 64 + l];
      acc[rb] = __builtin_amdgcn_mfma_f32_16x16x32_bf16(af, bfr, acc[rb], 0, 0, 0);
    }
    __syncthreads();
  }

#pragma unroll
  for (int rb = 0; rb < 4; ++rb) {
#pragma unroll
    for (int j = 0; j < 4; ++j) {
      int r = rb * 16 + g * 4 + j;
      float val = acc[rb][j] + qbk[r];
      logits[(size_t)r * S_LEN + scol] = val;
      float mx = val;
      mx = fmaxf(mx, __shfl_xor(mx, 1));
      mx = fmaxf(mx, __shfl_xor(mx, 2));
      mx = fmaxf(mx, __shfl_xor(mx, 4));
      mx = fmaxf(mx, __shfl_xor(mx, 8));
      if (l15 == 0) pmL[w * 64 + r] = mx;
    }
  }
  __syncthreads();
  if (t < 64) {
    float m0 = fmaxf(fmaxf(pmL[t], pmL[64 + t]), fmaxf(pmL[128 + t], pmL[192 + t]));
    pmax[(size_t)t * 1024 + wg] = m0;
  }
}

__global__ void k_gmax(const float* __restrict__ pmax, float* __restrict__ gmax) {
  int r = blockIdx.x, t = threadIdx.x;
  __shared__ float red[256];
  float m = -3.0e38f;
  for (int i = t; i < 1024; i += 256) m = fmaxf(m, pmax[(size_t)r * 1024 + i]);
  red[t] = m; __syncthreads();
  for (int s = 128; s > 0; s >>= 1) {
    if (t < s) red[t] = fmaxf(red[t], red[t + s]);
    __syncthreads();
  }
  if (t == 0) gmax[r] = red[0];
}

// E = exp(logits - gmax) as bf16, plus partial row sums
__global__ void k_make_e(const float* __restrict__ logits, const float* __restrict__ gmax,
                         u16* __restrict__ E, float* __restrict__ plsum) {
  int b = blockIdx.x, t = threadIdx.x;     // 512 blocks
  int r = b >> 3, sc = b & 7;
  float gm = gmax[r];
  size_t base = (size_t)r * S_LEN + sc * 8192 + t * 32;
  const float* lp = logits + base;
  u16* ep = E + base;
  float sum = 0.f;
#pragma unroll
  for (int gi = 0; gi < 4; ++gi) {
    f32x4 f0 = *(const f32x4*)(lp + gi * 8);
    f32x4 f1 = *(const f32x4*)(lp + gi * 8 + 4);
    float e[8];
#pragma unroll
    for (int i = 0; i < 4; ++i) { e[i] = expf(f0[i] - gm); e[4 + i] = expf(f1[i] - gm); }
    union { uint4 u4; u16 s[8]; } pk;
#pragma unroll
    for (int i = 0; i < 8; ++i) { sum += e[i]; pk.s[i] = f2bf(e[i]); }
    *(uint4*)(ep + gi * 8) = pk.u4;
  }
  __shared__ float red[256];
  red[t] = sum; __syncthreads();
  for (int s = 128; s > 0; s >>= 1) {
    if (t < s) red[t] += red[t + s];
    __syncthreads();
  }
  if (t == 0) plsum[r * 8 + sc] = red[0];
}

// split-K: pew[chunk][64][1024] = E[:, chunk] @ H[chunk, :]
__global__ __launch_bounds__(256, 4) void k_pass2(
    const float* __restrict__ h, const u16* __restrict__ E, float* __restrict__ pew) {
  int t = threadIdx.x;
  int chunk = blockIdx.x >> 3, ctile = blockIdx.x & 7;
  int w = t >> 6, l = t & 63;
  int g = l >> 4, l15 = l & 15;
  int c0 = ctile * 128 + w * 32;
  f32x4 acc[4][2];
#pragma unroll
  for (int rb = 0; rb < 4; ++rb)
#pragma unroll
    for (int cb = 0; cb < 2; ++cb) acc[rb][cb] = (f32x4){0.f, 0.f, 0.f, 0.f};

  int kbase = chunk * 512;
  for (int ks = 0; ks < 16; ++ks) {
    int k0 = kbase + ks * 32;
    bf16x8 af[4];
#pragma unroll
    for (int rb = 0; rb < 4; ++rb) {
      size_t eidx = (size_t)(rb * 16 + l15) * S_LEN + k0 + g * 8;
      uint4 u = *(const uint4*)(E + eidx);
      af[rb] = *(bf16x8*)&u;
    }
    bf16x8 bfb[2];
#pragma unroll
    for (int cb = 0; cb < 2; ++cb) {
      const float* hp = h + (size_t)(k0 + g * 8) * DM + c0 + cb * 16 + l15;
      float fb[8];
#pragma unroll
      for (int e = 0; e < 8; ++e) fb[e] = hp[(size_t)e * DM];
      bfb[cb] = pack_bf8(fb);
    }
#pragma unroll
    for (int rb = 0; rb < 4; ++rb)
#pragma unroll
      for (int cb = 0; cb < 2; ++cb)
        acc[rb][cb] = __builtin_amdgcn_mfma_f32_16x16x32_bf16(af[rb], bfb[cb], acc[rb][cb], 0, 0, 0);
  }
  float* pw = pew + (size_t)chunk * 65536;
#pragma unroll
  for (int rb = 0; rb < 4; ++rb)
#pragma unroll
    for (int cb = 0; cb < 2; ++cb)
#pragma unroll
      for (int j = 0; j < 4; ++j) {
        int r = rb * 16 + g * 4 + j;
        int c = c0 + cb * 16 + l15;
        pw[(size_t)r * 1024 + c] = acc[rb][cb][j];
      }
}

__global__ void k_red_ew(const float* __restrict__ pew, float* __restrict__ ew,
                         const float* __restrict__ plsum, float* __restrict__ lsum) {
  int idx = blockIdx.x * 256 + threadIdx.x;   // 65536
  const float* p = pew + idx;
  float s = 0.f;
#pragma unroll 8
  for (int ch = 0; ch < 128; ++ch) s += p[(size_t)ch * 65536];
  ew[idx] = s;
  if (blockIdx.x == 0 && threadIdx.x < 64) {
    float lv = 0.f;
#pragma unroll
    for (int i = 0; i < 8; ++i) lv += plsum[threadIdx.x * 8 + i];
    lsum[threadIdx.x] = lv;
  }
}

// out_attn[m, h*128+d] = (ew[r] @ wv[:, col] + l*bv) / (l + 1e-9)
__global__ void k_attn_out(const float* __restrict__ ew, const float* __restrict__ lsum,
                           const float* __restrict__ wv, const float* __restrict__ bv,
                           float* __restrict__ oatt) {
  int r = blockIdx.x, d = threadIdx.x;   // 64 x 128
  int m = r >> 3, hh = r & 7;
  int col = hh * 128 + d;
  float acc = 0.f;
  const float* er = ew + (size_t)r * 1024;
#pragma unroll 4
  for (int c = 0; c < 1024; ++c) acc += er[c] * wv[(size_t)c * DM + col];
  float lv = lsum[r];
  oatt[(size_t)m * DM + col] = (acc + lv * bv[col]) / (lv + 1e-9f);
}

__global__ void k_proj_o(const float* __restrict__ oatt, const float* __restrict__ wo,
                         const float* __restrict__ bo, float* __restrict__ o2) {
  int tid = blockIdx.x * 256 + threadIdx.x;   // 8192
  int m = tid >> 10, j = tid & 1023;
  float acc = bo[j];
  const float* om = oatt + (size_t)m * DM;
#pragma unroll 4
  for (int i = 0; i < DM; ++i) acc += om[i] * wo[(size_t)i * DM + j];
  o2[tid] = acc;
}

__global__ void k_ln_mlp1(const float* __restrict__ o2, const float* __restrict__ g,
                          const float* __restrict__ b, const float* __restrict__ w1,
                          const float* __restrict__ b1, float* __restrict__ h1) {
  int blk = blockIdx.x, t = threadIdx.x;   // 64 x 256
  int m = blk >> 3, jc = blk & 7;
  __shared__ float red[256], red2[256];
  const float* om = o2 + (size_t)m * DM;
  float s = 0.f, s2 = 0.f;
  for (int i = t; i < DM; i += 256) { float x = om[i]; s += x; s2 += x * x; }
  red[t] = s; red2[t] = s2; __syncthreads();
  for (int st = 128; st > 0; st >>= 1) {
    if (t < st) { red[t] += red[t + st]; red2[t] += red2[t + st]; }
    __syncthreads();
  }
  float mu = red[0] * (1.f / DM);
  float var = fmaxf(red2[0] * (1.f / DM) - mu * mu, 0.f);
  float rstd = rsqrtf(var + 1e-5f);
  int j = jc * 256 + t;
  float acc = b1[j];
#pragma unroll 4
  for (int i = 0; i < DM; ++i) {
    float xn = (om[i] - mu) * rstd * g[i] + b[i];
    acc += xn * w1[(size_t)i * HID_ + j];
  }
  h1[(size_t)m * HID_ + j] = 0.5f * acc * (1.f + erff(acc * 0.70710678118654752f));
}

__global__ void k_mlp2(const float* __restrict__ h1, const float* __restrict__ w2,
                       const float* __restrict__ b2, const float* __restrict__ o2,
                       float* __restrict__ out) {
  int tid = blockIdx.x * 256 + threadIdx.x;   // 8192
  int m = tid >> 10, j = tid & 1023;
  float acc = b2[j];
  const float* hm = h1 + (size_t)m * HID_;
#pragma unroll 4
  for (int i = 0; i < HID_; ++i) acc += hm[i] * w2[(size_t)i * DM + j];
  out[tid] = o2[tid] + acc;
}

__global__ void k_mvec(float* __restrict__ out) {
  int j = blockIdx.x * 256 + threadIdx.x;   // 1024
  float s = 0.f;
#pragma unroll
  for (int m = 0; m < 8; ++m) s += out[m * DM + j];
  out[8192 + j] = s * 0.125f;
}

extern "C" void kernel_launch(void* const* d_in, const int* in_sizes, int n_in,
                              void* d_out, int out_size, void* d_ws, size_t ws_size,
                              hipStream_t stream) {
  (void)in_sizes; (void)n_in; (void)out_size; (void)ws_size;
  const float* h   = (const float*)d_in[0];
  const float* lat = (const float*)d_in[1];
  const float* wq  = (const float*)d_in[2];
  const float* bq  = (const float*)d_in[3];
  const float* wk  = (const float*)d_in[4];
  const float* bk  = (const float*)d_in[5];
  const float* wv  = (const float*)d_in[6];
  const float* bv  = (const float*)d_in[7];
  const float* wo  = (const float*)d_in[8];
  const float* bo  = (const float*)d_in[9];
  const float* lng = (const float*)d_in[10];
  const float* lnb = (const float*)d_in[11];
  const float* w1  = (const float*)d_in[12];
  const float* b1  = (const float*)d_in[13];
  const float* w2  = (const float*)d_in[14];
  const float* b2  = (const float*)d_in[15];
  float* out = (float*)d_out;
  char* ws = (char*)d_ws;

  float* q      = (float*)(ws + WS_Q);
  u16*   qka    = (u16*)  (ws + WS_QKA);
  float* qbk    = (float*)(ws + WS_QBK);
  float* gmax   = (float*)(ws + WS_GMAX);
  float* lsum   = (float*)(ws + WS_LSUM);
  float* plsum  = (float*)(ws + WS_PLSUM);
  float* ew     = (float*)(ws + WS_EW);
  float* pmax   = (float*)(ws + WS_PMAX);
  float* oatt   = (float*)(ws + WS_OATT);
  float* o2     = (float*)(ws + WS_O2);
  float* h1     = (float*)(ws + WS_H1);
  float* logits = (float*)(ws + WS_LOGITS);
  float* pew    = (float*)(ws + WS_PEW);
  u16*   E      = (u16*)  (ws + WS_E);

  hipLaunchKernelGGL(k_proj_q,   dim3(32),   dim3(256), 0, stream, lat, wq, bq, q);
  hipLaunchKernelGGL(k_fold_qk,  dim3(256),  dim3(256), 0, stream, q, wk, bk, qka, qbk);
  hipLaunchKernelGGL(k_logits,   dim3(1024), dim3(256), 0, stream, h, qka, qbk, logits, pmax);
  hipLaunchKernelGGL(k_gmax,     dim3(64),   dim3(256), 0, stream, pmax, gmax);
  hipLaunchKernelGGL(k_make_e,   dim3(512),  dim3(256), 0, stream, logits, gmax, E, plsum);
  hipLaunchKernelGGL(k_pass2,    dim3(1024), dim3(256), 0, stream, h, E, pew);
  hipLaunchKernelGGL(k_red_ew,   dim3(256),  dim3(256), 0, stream, pew, ew, plsum, lsum);
  hipLaunchKernelGGL(k_attn_out, dim3(64),   dim3(128), 0, stream, ew, lsum, wv, bv, oatt);
  hipLaunchKernelGGL(k_proj_o,   dim3(32),   dim3(256), 0, stream, oatt, wo, bo, o2);
  hipLaunchKernelGGL(k_ln_mlp1,  dim3(64),   dim3(256), 0, stream, o2, lng, lnb, w1, b1, h1);
  hipLaunchKernelGGL(k_mlp2,     dim3(32),   dim3(256), 0, stream, h1, w2, b2, o2, out);
  hipLaunchKernelGGL(k_mvec,     dim3(4),    dim3(256), 0, stream, out);
}

// Round 3
// 583.785 us; speedup vs baseline: 2.1455x; 2.1455x over previous
//
#include <hip/hip_runtime.h>
#include <stdint.h>
#include <math.h>

#define S_LEN   65536
#define DM      1024
#define HD_     128
#define HID_    2048
#define SCALE_F 0.08838834764831845f

typedef float          f32x4  __attribute__((ext_vector_type(4)));
typedef short          bf16x8 __attribute__((ext_vector_type(8)));
typedef unsigned short u16;

__device__ __forceinline__ u16 f2bf(float f) {
  union { float f; uint32_t u; } v; v.f = f;
  uint32_t u = v.u;
  u += 0x7FFFu + ((u >> 16) & 1u);
  return (u16)(u >> 16);
}

__device__ __forceinline__ bf16x8 pack_bf8(const float* f) {
  union { bf16x8 v; u16 s[8]; } r;
#pragma unroll
  for (int i = 0; i < 8; ++i) r.s[i] = f2bf(f[i]);
  return r.v;
}

// ---------------- workspace layout (bytes) ----------------
#define WS_Q      0u          // 8192 f32
#define WS_QKA    32768u      // 65536 bf16 (fragment-linear)
#define WS_QBK    163840u     // 64 f32
#define WS_GMAX   164096u     // 64 f32
#define WS_LSUM   164352u     // 64 f32
#define WS_PLSUM  164608u     // 512 f32
#define WS_XN     167936u     // 8192 f32
#define WS_EWH    430080u     // 65536 f32 (reuses pmax region; pmax dead after k_gmax)
#define WS_PMAX   430080u     // 65536 f32 (dead after k_gmax)
#define WS_OATT   692224u     // 8192 f32
#define WS_O2     724992u     // 8192 f32
#define WS_H1     757760u     // 16384 f32
#define WS_PBASE  1048576u    // partial slabs (<=4MB), time-shared with logits/pew
#define WS_LOGITS 1048576u    // 64*65536 f32 (dead after k_make_e)
#define WS_PEW    1048576u    // 128*64*1024 f32 (reuses logits region, dead after k_red_ew)
#define WS_E      34603008u   // 64*65536 bf16

// ---------- split-K GEMM, 8 rows: P[kb][8][C] = X[8, kslice] @ W[kslice, C] ----------
// grid = ncg * NKB, block 256. Block covers cols [cg*512, +512), k in [kb*KS, +KS).
// X reads are wave-uniform -> s_load; W reads float2 coalesced.
template<int KS>
__global__ __launch_bounds__(256) void k_sk8(const float* __restrict__ X,
                                             const float* __restrict__ W,
                                             float* __restrict__ P,
                                             int C, int K, int ncg) {
  int cg = blockIdx.x % ncg, kb = blockIdx.x / ncg;
  int c = (cg << 9) + threadIdx.x * 2;
  int k0 = kb * KS;
  float2 acc[8];
#pragma unroll
  for (int r = 0; r < 8; ++r) { acc[r].x = 0.f; acc[r].y = 0.f; }
  const float* wp = W + (size_t)k0 * C + c;
#pragma unroll 8
  for (int i = 0; i < KS; ++i) {
    float2 w = *(const float2*)wp; wp += C;
#pragma unroll
    for (int r = 0; r < 8; ++r) {
      float xv = X[r * K + k0 + i];
      acc[r].x += xv * w.x; acc[r].y += xv * w.y;
    }
  }
  float* pp = P + (size_t)(kb * 8) * C + c;
#pragma unroll
  for (int r = 0; r < 8; ++r) *(float2*)(pp + (size_t)r * C) = acc[r];
}

// ---------- per-head split-K for attention output: Pa[slab][8][1024] ----------
// ewh layout: ewh[h*8192 + k*8 + m].  grid = 8 * NKB_A (=16) -> 128 blocks.
__global__ __launch_bounds__(256) void k_sk8h(const float* __restrict__ ewh,
                                              const float* __restrict__ wv,
                                              float* __restrict__ Pa) {
  int h = blockIdx.x & 7, kb = blockIdx.x >> 3;
  int lane = threadIdx.x & 63, q4 = threadIdx.x >> 6;
  int c = h * 128 + lane * 2;
  int k0 = kb * 64 + q4 * 16;
  const float* xp = ewh + h * 8192 + k0 * 8;
  const float* wp = wv + (size_t)k0 * 1024 + c;
  float2 acc[8];
#pragma unroll
  for (int m = 0; m < 8; ++m) { acc[m].x = 0.f; acc[m].y = 0.f; }
#pragma unroll
  for (int i = 0; i < 16; ++i) {
    float2 w = *(const float2*)wp; wp += 1024;
#pragma unroll
    for (int m = 0; m < 8; ++m) {
      float xv = xp[i * 8 + m];
      acc[m].x += xv * w.x; acc[m].y += xv * w.y;
    }
  }
  int slab = kb * 4 + q4;  // 64 slabs
  float* pp = Pa + (size_t)(slab * 8) * 1024 + c;
#pragma unroll
  for (int m = 0; m < 8; ++m) *(float2*)(pp + (size_t)m * 1024) = acc[m];
}

// ---------- reduce kernels (L2-hot partials) ----------
__global__ void k_red_q(const float* __restrict__ P, const float* __restrict__ bq,
                        float* __restrict__ q) {
  int idx = blockIdx.x * 256 + threadIdx.x;   // 8192
  int m = idx >> 10, c = idx & 1023;
  float s = bq[c];
#pragma unroll 8
  for (int ks = 0; ks < 32; ++ks) s += P[(size_t)(ks * 8 + m) * 1024 + c];
  q[idx] = s;
}

__global__ void k_qbk(const float* __restrict__ q, const float* __restrict__ bk,
                      float* __restrict__ qbk) {
  int t = threadIdx.x;        // 1 block, 256
  int r = t >> 2, qr = t & 3;
  int m = r >> 3, h = r & 7;
  float s = 0.f;
  int d0 = qr * 32;
#pragma unroll
  for (int d = 0; d < 32; ++d)
    s += q[m * 1024 + h * 128 + d0 + d] * bk[h * 128 + d0 + d];
  s += __shfl_xor(s, 1);
  s += __shfl_xor(s, 2);
  if (qr == 0) qbk[r] = s * SCALE_F;
}

// per-head LDS-tiled fold: qka (fragment-linear bf16) = scale * q_head @ wk_head^T
__global__ __launch_bounds__(256) void k_foldqk(const float* __restrict__ q,
                                                const float* __restrict__ wk,
                                                u16* __restrict__ qka) {
  __shared__ float tile[64 * 129];
  int h = blockIdx.x & 7, ib = blockIdx.x >> 3;  // ib<16
  int i0 = ib * 64;
  int t = threadIdx.x;
  {
    int ii = t >> 2, dg = (t & 3) * 32;
    const float* src = wk + (size_t)(i0 + ii) * 1024 + h * 128 + dg;
    float* dst = tile + ii * 129 + dg;
#pragma unroll
    for (int u = 0; u < 8; ++u) {
      f32x4 v = *(const f32x4*)(src + u * 4);
      dst[u * 4 + 0] = v[0]; dst[u * 4 + 1] = v[1];
      dst[u * 4 + 2] = v[2]; dst[u * 4 + 3] = v[3];
    }
  }
  __syncthreads();
  int ii = t & 63, q4 = t >> 6;
  int i = i0 + ii;
  float a0 = 0.f, a1 = 0.f;
#pragma unroll 16
  for (int d = 0; d < 128; ++d) {
    float w = tile[ii * 129 + d];
    a0 += q[(q4 * 2 + 0) * 1024 + h * 128 + d] * w;
    a1 += q[(q4 * 2 + 1) * 1024 + h * 128 + d] * w;
  }
#pragma unroll
  for (int j = 0; j < 2; ++j) {
    int m = q4 * 2 + j;
    int r = m * 8 + h;
    float val = (j == 0 ? a0 : a1) * SCALE_F;
    int K0 = i >> 5, rb = r >> 4, hi = (i & 31) >> 3, e = i & 7, l16 = r & 15;
    int lane = hi * 16 + l16;
    qka[(((K0 * 4 + rb) * 64 + lane) << 3) + e] = f2bf(val);
  }
}

// logits[64, S] = qkfold @ H^T (+qbk), plus per-tile row max
__global__ __launch_bounds__(256, 4) void k_logits(
    const float* __restrict__ h, const u16* __restrict__ qka,
    const float* __restrict__ qbk, float* __restrict__ logits,
    float* __restrict__ pmax) {
  __shared__ __align__(16) u16 Abuf[2][2048];
  __shared__ float pmL[4 * 64];
  int t = threadIdx.x, wg = blockIdx.x;
  int w = t >> 6, l = t & 63;
  int g = l >> 4, l15 = l & 15;
  int scol = wg * 64 + w * 16 + l15;

  ((uint4*)Abuf[0])[t] = ((const uint4*)qka)[t];
  __syncthreads();

  f32x4 acc[4];
#pragma unroll
  for (int rb = 0; rb < 4; ++rb) acc[rb] = (f32x4){0.f, 0.f, 0.f, 0.f};

  for (int ks = 0; ks < 32; ++ks) {
    int buf = ks & 1;
    if (ks + 1 < 32)
      ((uint4*)Abuf[buf ^ 1])[t] = ((const uint4*)(qka + (size_t)(ks + 1) * 2048))[t];
    const float* hp = h + (size_t)scol * DM + ks * 32 + g * 8;
    float fb[8];
    f32x4 f0 = *(const f32x4*)hp;
    f32x4 f1 = *(const f32x4*)(hp + 4);
    fb[0]=f0[0]; fb[1]=f0[1]; fb[2]=f0[2]; fb[3]=f0[3];
    fb[4]=f1[0]; fb[5]=f1[1]; fb[6]=f1[2]; fb[7]=f1[3];
    bf16x8 bfr = pack_bf8(fb);
    const bf16x8* ap = (const bf16x8*)Abuf[buf];
#pragma unroll
    for (int rb = 0; rb < 4; ++rb) {
      bf16x8 af = ap[rb * 64 + l];
      acc[rb] = __builtin_amdgcn_mfma_f32_16x16x32_bf16(af, bfr, acc[rb], 0, 0, 0);
    }
    __syncthreads();
  }

#pragma unroll
  for (int rb = 0; rb < 4; ++rb) {
#pragma unroll
    for (int j = 0; j < 4; ++j) {
      int r = rb * 16 + g * 4 + j;
      float val = acc[rb][j] + qbk[r];
      logits[(size_t)r * S_LEN + scol] = val;
      float mx = val;
      mx = fmaxf(mx, __shfl_xor(mx, 1));
      mx = fmaxf(mx, __shfl_xor(mx, 2));
      mx = fmaxf(mx, __shfl_xor(mx, 4));
      mx = fmaxf(mx, __shfl_xor(mx, 8));
      if (l15 == 0) pmL[w * 64 + r] = mx;
    }
  }
  __syncthreads();
  if (t < 64) {
    float m0 = fmaxf(fmaxf(pmL[t], pmL[64 + t]), fmaxf(pmL[128 + t], pmL[192 + t]));
    pmax[(size_t)t * 1024 + wg] = m0;
  }
}

__global__ void k_gmax(const float* __restrict__ pmax, float* __restrict__ gmax) {
  int r = blockIdx.x, t = threadIdx.x;
  __shared__ float red[256];
  float m = -3.0e38f;
  for (int i = t; i < 1024; i += 256) m = fmaxf(m, pmax[(size_t)r * 1024 + i]);
  red[t] = m; __syncthreads();
  for (int s = 128; s > 0; s >>= 1) {
    if (t < s) red[t] = fmaxf(red[t], red[t + s]);
    __syncthreads();
  }
  if (t == 0) gmax[r] = red[0];
}

// E = exp(logits - gmax) as bf16, plus partial row sums
__global__ void k_make_e(const float* __restrict__ logits, const float* __restrict__ gmax,
                         u16* __restrict__ E, float* __restrict__ plsum) {
  int b = blockIdx.x, t = threadIdx.x;     // 512 blocks
  int r = b >> 3, sc = b & 7;
  float gm = gmax[r];
  size_t base = (size_t)r * S_LEN + sc * 8192 + t * 32;
  const float* lp = logits + base;
  u16* ep = E + base;
  float sum = 0.f;
#pragma unroll
  for (int gi = 0; gi < 4; ++gi) {
    f32x4 f0 = *(const f32x4*)(lp + gi * 8);
    f32x4 f1 = *(const f32x4*)(lp + gi * 8 + 4);
    float e[8];
#pragma unroll
    for (int i = 0; i < 4; ++i) { e[i] = expf(f0[i] - gm); e[4 + i] = expf(f1[i] - gm); }
    union { uint4 u4; u16 s[8]; } pk;
#pragma unroll
    for (int i = 0; i < 8; ++i) { sum += e[i]; pk.s[i] = f2bf(e[i]); }
    *(uint4*)(ep + gi * 8) = pk.u4;
  }
  __shared__ float red[256];
  red[t] = sum; __syncthreads();
  for (int s = 128; s > 0; s >>= 1) {
    if (t < s) red[t] += red[t + s];
    __syncthreads();
  }
  if (t == 0) plsum[r * 8 + sc] = red[0];
}

// split-K: pew[chunk][64][1024] = E[:, chunk] @ H[chunk, :]
__global__ __launch_bounds__(256, 4) void k_pass2(
    const float* __restrict__ h, const u16* __restrict__ E, float* __restrict__ pew) {
  int t = threadIdx.x;
  int chunk = blockIdx.x >> 3, ctile = blockIdx.x & 7;
  int w = t >> 6, l = t & 63;
  int g = l >> 4, l15 = l & 15;
  int c0 = ctile * 128 + w * 32;
  f32x4 acc[4][2];
#pragma unroll
  for (int rb = 0; rb < 4; ++rb)
#pragma unroll
    for (int cb = 0; cb < 2; ++cb) acc[rb][cb] = (f32x4){0.f, 0.f, 0.f, 0.f};

  int kbase = chunk * 512;
  for (int ks = 0; ks < 16; ++ks) {
    int k0 = kbase + ks * 32;
    bf16x8 af[4];
#pragma unroll
    for (int rb = 0; rb < 4; ++rb) {
      size_t eidx = (size_t)(rb * 16 + l15) * S_LEN + k0 + g * 8;
      uint4 u = *(const uint4*)(E + eidx);
      af[rb] = *(bf16x8*)&u;
    }
    bf16x8 bfb[2];
#pragma unroll
    for (int cb = 0; cb < 2; ++cb) {
      const float* hp = h + (size_t)(k0 + g * 8) * DM + c0 + cb * 16 + l15;
      float fb[8];
#pragma unroll
      for (int e = 0; e < 8; ++e) fb[e] = hp[(size_t)e * DM];
      bfb[cb] = pack_bf8(fb);
    }
#pragma unroll
    for (int rb = 0; rb < 4; ++rb)
#pragma unroll
      for (int cb = 0; cb < 2; ++cb)
        acc[rb][cb] = __builtin_amdgcn_mfma_f32_16x16x32_bf16(af[rb], bfb[cb], acc[rb][cb], 0, 0, 0);
  }
  float* pw = pew + (size_t)chunk * 65536;
#pragma unroll
  for (int rb = 0; rb < 4; ++rb)
#pragma unroll
    for (int cb = 0; cb < 2; ++cb)
#pragma unroll
      for (int j = 0; j < 4; ++j) {
        int r = rb * 16 + g * 4 + j;
        int c = c0 + cb * 16 + l15;
        pw[(size_t)r * 1024 + c] = acc[rb][cb][j];
      }
}

// reduce pew -> ewh (head-major layout for k_sk8h), plus lsum
__global__ void k_red_ew(const float* __restrict__ pew, float* __restrict__ ewh,
                         const float* __restrict__ plsum, float* __restrict__ lsum) {
  int idx = blockIdx.x * 256 + threadIdx.x;   // 65536
  const float* p = pew + idx;
  float s = 0.f;
#pragma unroll 8
  for (int ch = 0; ch < 128; ++ch) s += p[(size_t)ch * 65536];
  int r = idx >> 10, c = idx & 1023;
  int m = r >> 3, hh = r & 7;
  ewh[hh * 8192 + c * 8 + m] = s;
  if (blockIdx.x == 0 && threadIdx.x < 64) {
    float lv = 0.f;
#pragma unroll
    for (int i = 0; i < 8; ++i) lv += plsum[threadIdx.x * 8 + i];
    lsum[threadIdx.x] = lv;
  }
}

__global__ void k_red_attn(const float* __restrict__ Pa, const float* __restrict__ lsum,
                           const float* __restrict__ bv, float* __restrict__ oatt) {
  int idx = blockIdx.x * 256 + threadIdx.x;   // 8192
  int m = idx >> 10, col = idx & 1023;
  int r = m * 8 + (col >> 7);
  float s = 0.f;
#pragma unroll 8
  for (int ks = 0; ks < 64; ++ks) s += Pa[(size_t)(ks * 8 + m) * 1024 + col];
  float lv = lsum[r];
  oatt[idx] = (s + lv * bv[col]) / (lv + 1e-9f);
}

__global__ void k_red_o2(const float* __restrict__ P, const float* __restrict__ bo,
                         float* __restrict__ o2) {
  int idx = blockIdx.x * 256 + threadIdx.x;   // 8192
  int m = idx >> 10, c = idx & 1023;
  float s = bo[c];
#pragma unroll 8
  for (int ks = 0; ks < 32; ++ks) s += P[(size_t)(ks * 8 + m) * 1024 + c];
  o2[idx] = s;
}

__global__ void k_ln(const float* __restrict__ o2, const float* __restrict__ g,
                     const float* __restrict__ b, float* __restrict__ xn) {
  int m = blockIdx.x, t = threadIdx.x;   // 8 x 256
  __shared__ float red[256], red2[256];
  f32x4 x = ((const f32x4*)(o2 + m * 1024))[t];
  float s = x[0] + x[1] + x[2] + x[3];
  float s2 = x[0]*x[0] + x[1]*x[1] + x[2]*x[2] + x[3]*x[3];
  red[t] = s; red2[t] = s2; __syncthreads();
  for (int st = 128; st > 0; st >>= 1) {
    if (t < st) { red[t] += red[t + st]; red2[t] += red2[t + st]; }
    __syncthreads();
  }
  float mu = red[0] * (1.f / DM);
  float var = fmaxf(red2[0] * (1.f / DM) - mu * mu, 0.f);
  float rstd = rsqrtf(var + 1e-5f);
  f32x4 gg = ((const f32x4*)g)[t];
  f32x4 bb = ((const f32x4*)b)[t];
  f32x4 o;
#pragma unroll
  for (int j = 0; j < 4; ++j) o[j] = (x[j] - mu) * rstd * gg[j] + bb[j];
  ((f32x4*)(xn + m * 1024))[t] = o;
}

__global__ void k_red_h1(const float* __restrict__ P, const float* __restrict__ b1,
                         float* __restrict__ h1) {
  int idx = blockIdx.x * 256 + threadIdx.x;   // 16384
  int m = idx >> 11, j = idx & 2047;
  float s = b1[j];
#pragma unroll 8
  for (int ks = 0; ks < 32; ++ks) s += P[(size_t)(ks * 8 + m) * 2048 + j];
  h1[idx] = 0.5f * s * (1.f + erff(s * 0.70710678118654752f));
}

__global__ void k_red_out(const float* __restrict__ P, const float* __restrict__ b2,
                          const float* __restrict__ o2, float* __restrict__ out) {
  int idx = blockIdx.x * 256 + threadIdx.x;   // 8192
  int m = idx >> 10, c = idx & 1023;
  float s = b2[c];
#pragma unroll 8
  for (int ks = 0; ks < 64; ++ks) s += P[(size_t)(ks * 8 + m) * 1024 + c];
  out[idx] = o2[idx] + s;
}

__global__ void k_mvec(float* __restrict__ out) {
  int j = blockIdx.x * 256 + threadIdx.x;   // 1024
  float s = 0.f;
#pragma unroll
  for (int m = 0; m < 8; ++m) s += out[m * DM + j];
  out[8192 + j] = s * 0.125f;
}

extern "C" void kernel_launch(void* const* d_in, const int* in_sizes, int n_in,
                              void* d_out, int out_size, void* d_ws, size_t ws_size,
                              hipStream_t stream) {
  (void)in_sizes; (void)n_in; (void)out_size; (void)ws_size;
  const float* h   = (const float*)d_in[0];
  const float* lat = (const float*)d_in[1];
  const float* wq  = (const float*)d_in[2];
  const float* bq  = (const float*)d_in[3];
  const float* wk  = (const float*)d_in[4];
  const float* bk  = (const float*)d_in[5];
  const float* wv  = (const float*)d_in[6];
  const float* bv  = (const float*)d_in[7];
  const float* wo  = (const float*)d_in[8];
  const float* bo  = (const float*)d_in[9];
  const float* lng = (const float*)d_in[10];
  const float* lnb = (const float*)d_in[11];
  const float* w1  = (const float*)d_in[12];
  const float* b1  = (const float*)d_in[13];
  const float* w2  = (const float*)d_in[14];
  const float* b2  = (const float*)d_in[15];
  float* out = (float*)d_out;
  char* ws = (char*)d_ws;

  float* q      = (float*)(ws + WS_Q);
  u16*   qka    = (u16*)  (ws + WS_QKA);
  float* qbk    = (float*)(ws + WS_QBK);
  float* gmax   = (float*)(ws + WS_GMAX);
  float* lsum   = (float*)(ws + WS_LSUM);
  float* plsum  = (float*)(ws + WS_PLSUM);
  float* xn     = (float*)(ws + WS_XN);
  float* ewh    = (float*)(ws + WS_EWH);
  float* pmax   = (float*)(ws + WS_PMAX);
  float* oatt   = (float*)(ws + WS_OATT);
  float* o2     = (float*)(ws + WS_O2);
  float* h1     = (float*)(ws + WS_H1);
  float* P      = (float*)(ws + WS_PBASE);
  float* logits = (float*)(ws + WS_LOGITS);
  float* pew    = (float*)(ws + WS_PEW);
  u16*   E      = (u16*)  (ws + WS_E);

  // ---- q = lat @ wq + bq (split-K) ----
  hipLaunchKernelGGL((k_sk8<32>), dim3(64),  dim3(256), 0, stream, lat, wq, P, 1024, 1024, 2);
  hipLaunchKernelGGL(k_red_q,     dim3(32),  dim3(256), 0, stream, P, bq, q);
  hipLaunchKernelGGL(k_qbk,       dim3(1),   dim3(256), 0, stream, q, bk, qbk);
  // ---- qkfold (per-head LDS-tiled) ----
  hipLaunchKernelGGL(k_foldqk,    dim3(128), dim3(256), 0, stream, q, wk, qka);
  // ---- pass 1: logits + global max ----
  hipLaunchKernelGGL(k_logits,    dim3(1024), dim3(256), 0, stream, h, qka, qbk, logits, pmax);
  hipLaunchKernelGGL(k_gmax,      dim3(64),  dim3(256), 0, stream, pmax, gmax);
  hipLaunchKernelGGL(k_make_e,    dim3(512), dim3(256), 0, stream, logits, gmax, E, plsum);
  // ---- pass 2: EW partials + reduce ----
  hipLaunchKernelGGL(k_pass2,     dim3(1024), dim3(256), 0, stream, h, E, pew);
  hipLaunchKernelGGL(k_red_ew,    dim3(256), dim3(256), 0, stream, pew, ewh, plsum, lsum);
  // ---- attention output: oatt = (ew @ wv + l*bv) / (l+eps) ----
  hipLaunchKernelGGL(k_sk8h,      dim3(128), dim3(256), 0, stream, ewh, wv, P);
  hipLaunchKernelGGL(k_red_attn,  dim3(32),  dim3(256), 0, stream, P, lsum, bv, oatt);
  // ---- o2 = oatt @ wo + bo ----
  hipLaunchKernelGGL((k_sk8<32>), dim3(64),  dim3(256), 0, stream, oatt, wo, P, 1024, 1024, 2);
  hipLaunchKernelGGL(k_red_o2,    dim3(32),  dim3(256), 0, stream, P, bo, o2);
  // ---- MLP ----
  hipLaunchKernelGGL(k_ln,        dim3(8),   dim3(256), 0, stream, o2, lng, lnb, xn);
  hipLaunchKernelGGL((k_sk8<32>), dim3(128), dim3(256), 0, stream, xn, w1, P, 2048, 1024, 4);
  hipLaunchKernelGGL(k_red_h1,    dim3(64),  dim3(256), 0, stream, P, b1, h1);
  hipLaunchKernelGGL((k_sk8<32>), dim3(128), dim3(256), 0, stream, h1, w2, P, 1024, 2048, 2);
  hipLaunchKernelGGL(k_red_out,   dim3(32),  dim3(256), 0, stream, P, b2, o2, out);
  hipLaunchKernelGGL(k_mvec,      dim3(4),   dim3(256), 0, stream, out);
}

// Round 4
// 563.371 us; speedup vs baseline: 2.2232x; 1.0362x over previous
//
#include <hip/hip_runtime.h>
#include <stdint.h>
#include <math.h>

#define S_LEN   65536
#define DM      1024
#define HD_     128
#define HID_    2048
#define SCALE_F 0.08838834764831845f

typedef float          f32x4  __attribute__((ext_vector_type(4)));
typedef short          bf16x8 __attribute__((ext_vector_type(8)));
typedef unsigned short u16;

__device__ __forceinline__ u16 f2bf(float f) {
  union { float f; uint32_t u; } v; v.f = f;
  uint32_t u = v.u;
  u += 0x7FFFu + ((u >> 16) & 1u);
  return (u16)(u >> 16);
}

__device__ __forceinline__ bf16x8 pack_bf8(const float* f) {
  union { bf16x8 v; u16 s[8]; } r;
#pragma unroll
  for (int i = 0; i < 8; ++i) r.s[i] = f2bf(f[i]);
  return r.v;
}

// ---------------- workspace layout (bytes) ----------------
#define WS_Q      0u          // 8192 f32
#define WS_QKA    32768u      // 65536 bf16 (fragment-linear)
#define WS_QBK    163840u     // 64 f32
#define WS_LSUM   164352u     // 64 f32
#define WS_PLSUM  164608u     // 512 f32
#define WS_XN     167936u     // 8192 f32
#define WS_EWH    430080u     // 65536 f32
#define WS_PMAX   698368u     // 65536 f32
#define WS_OATT   960512u     // 8192 f32
#define WS_O2     993280u     // 8192 f32
#define WS_H1     1026048u    // 16384 f32
#define WS_PBASE  2097152u    // partial slabs (<=2MB each), time-shared with logits/pew
#define WS_LOGITS 2097152u    // 64*65536 f32 (dead after k_make_e)
#define WS_PEW    2097152u    // 64*64*1024 f32 (reuses logits region, dead after k_red_ew)
#define WS_E      34603008u   // 64*65536 bf16

// ---------- split-K GEMM, 8 rows: P[kb][8][C] = X[8, kslice] @ W[kslice, C] ----------
template<int KS>
__global__ __launch_bounds__(256) void k_sk8(const float* __restrict__ X,
                                             const float* __restrict__ W,
                                             float* __restrict__ P,
                                             int C, int K, int ncg) {
  int cg = blockIdx.x % ncg, kb = blockIdx.x / ncg;
  int c = (cg << 9) + threadIdx.x * 2;
  int k0 = kb * KS;
  float2 acc[8];
#pragma unroll
  for (int r = 0; r < 8; ++r) { acc[r].x = 0.f; acc[r].y = 0.f; }
  const float* wp = W + (size_t)k0 * C + c;
#pragma unroll 8
  for (int i = 0; i < KS; ++i) {
    float2 w = *(const float2*)wp; wp += C;
#pragma unroll
    for (int r = 0; r < 8; ++r) {
      float xv = X[r * K + k0 + i];
      acc[r].x += xv * w.x; acc[r].y += xv * w.y;
    }
  }
  float* pp = P + (size_t)(kb * 8) * C + c;
#pragma unroll
  for (int r = 0; r < 8; ++r) *(float2*)(pp + (size_t)r * C) = acc[r];
}

// ---------- per-head split-K for attention output ----------
__global__ __launch_bounds__(256) void k_sk8h(const float* __restrict__ ewh,
                                              const float* __restrict__ wv,
                                              float* __restrict__ Pa) {
  int h = blockIdx.x & 7, kb = blockIdx.x >> 3;
  int lane = threadIdx.x & 63, q4 = threadIdx.x >> 6;
  int c = h * 128 + lane * 2;
  int k0 = kb * 64 + q4 * 16;
  const float* xp = ewh + h * 8192 + k0 * 8;
  const float* wp = wv + (size_t)k0 * 1024 + c;
  float2 acc[8];
#pragma unroll
  for (int m = 0; m < 8; ++m) { acc[m].x = 0.f; acc[m].y = 0.f; }
#pragma unroll
  for (int i = 0; i < 16; ++i) {
    float2 w = *(const float2*)wp; wp += 1024;
#pragma unroll
    for (int m = 0; m < 8; ++m) {
      float xv = xp[i * 8 + m];
      acc[m].x += xv * w.x; acc[m].y += xv * w.y;
    }
  }
  int slab = kb * 4 + q4;  // 64 slabs
  float* pp = Pa + (size_t)(slab * 8) * 1024 + c;
#pragma unroll
  for (int m = 0; m < 8; ++m) *(float2*)(pp + (size_t)m * 1024) = acc[m];
}

__global__ void k_red_q(const float* __restrict__ P, const float* __restrict__ bq,
                        float* __restrict__ q) {
  int idx = blockIdx.x * 256 + threadIdx.x;   // 8192
  int m = idx >> 10, c = idx & 1023;
  float s = bq[c];
#pragma unroll 8
  for (int ks = 0; ks < 32; ++ks) s += P[(size_t)(ks * 8 + m) * 1024 + c];
  q[idx] = s;
}

// per-head LDS-tiled fold + qbk (ib==0 blocks)
__global__ __launch_bounds__(256) void k_foldqk(const float* __restrict__ q,
                                                const float* __restrict__ wk,
                                                const float* __restrict__ bk,
                                                u16* __restrict__ qka,
                                                float* __restrict__ qbk) {
  __shared__ float tile[64 * 129];
  int h = blockIdx.x & 7, ib = blockIdx.x >> 3;  // ib<16
  int i0 = ib * 64;
  int t = threadIdx.x;
  if (ib == 0 && t < 64) {
    int m = t >> 3, part = t & 7;
    float s = 0.f;
#pragma unroll
    for (int d = 0; d < 16; ++d)
      s += q[m * 1024 + h * 128 + part * 16 + d] * bk[h * 128 + part * 16 + d];
    s += __shfl_xor(s, 1);
    s += __shfl_xor(s, 2);
    s += __shfl_xor(s, 4);
    if (part == 0) qbk[m * 8 + h] = s * SCALE_F;
  }
  {
    int ii = t >> 2, dg = (t & 3) * 32;
    const float* src = wk + (size_t)(i0 + ii) * 1024 + h * 128 + dg;
    float* dst = tile + ii * 129 + dg;
#pragma unroll
    for (int u = 0; u < 8; ++u) {
      f32x4 v = *(const f32x4*)(src + u * 4);
      dst[u * 4 + 0] = v[0]; dst[u * 4 + 1] = v[1];
      dst[u * 4 + 2] = v[2]; dst[u * 4 + 3] = v[3];
    }
  }
  __syncthreads();
  int ii = t & 63, q4 = t >> 6;
  int i = i0 + ii;
  float a0 = 0.f, a1 = 0.f;
#pragma unroll 16
  for (int d = 0; d < 128; ++d) {
    float w = tile[ii * 129 + d];
    a0 += q[(q4 * 2 + 0) * 1024 + h * 128 + d] * w;
    a1 += q[(q4 * 2 + 1) * 1024 + h * 128 + d] * w;
  }
#pragma unroll
  for (int j = 0; j < 2; ++j) {
    int m = q4 * 2 + j;
    int r = m * 8 + h;
    float val = (j == 0 ? a0 : a1) * SCALE_F;
    int K0 = i >> 5, rb = r >> 4, hi = (i & 31) >> 3, e = i & 7, l16 = r & 15;
    int lane = hi * 16 + l16;
    qka[(((K0 * 4 + rb) * 64 + lane) << 3) + e] = f2bf(val);
  }
}

// logits[64, S] = qkfold @ H^T (+qbk). Barrier-free: A-frags straight from L2.
__global__ __launch_bounds__(256) void k_logits(
    const float* __restrict__ h, const u16* __restrict__ qka,
    const float* __restrict__ qbk, float* __restrict__ logits,
    float* __restrict__ pmax) {
  __shared__ float pmL[4 * 64];
  int t = threadIdx.x, wg = blockIdx.x;
  int w = t >> 6, l = t & 63;
  int g = l >> 4, l15 = l & 15;
  int scol = wg * 64 + w * 16 + l15;
  const bf16x8* qf = (const bf16x8*)qka;

  f32x4 acc[4];
#pragma unroll
  for (int rb = 0; rb < 4; ++rb) acc[rb] = (f32x4){0.f, 0.f, 0.f, 0.f};

#pragma unroll 2
  for (int ks = 0; ks < 32; ++ks) {
    const float* hp = h + (size_t)scol * DM + ks * 32 + g * 8;
    float fb[8];
    f32x4 f0 = *(const f32x4*)hp;
    f32x4 f1 = *(const f32x4*)(hp + 4);
    fb[0]=f0[0]; fb[1]=f0[1]; fb[2]=f0[2]; fb[3]=f0[3];
    fb[4]=f1[0]; fb[5]=f1[1]; fb[6]=f1[2]; fb[7]=f1[3];
    bf16x8 bfr = pack_bf8(fb);
#pragma unroll
    for (int rb = 0; rb < 4; ++rb) {
      bf16x8 af = qf[(ks * 4 + rb) * 64 + l];
      acc[rb] = __builtin_amdgcn_mfma_f32_16x16x32_bf16(af, bfr, acc[rb], 0, 0, 0);
    }
  }

#pragma unroll
  for (int rb = 0; rb < 4; ++rb) {
#pragma unroll
    for (int j = 0; j < 4; ++j) {
      int r = rb * 16 + g * 4 + j;
      float val = acc[rb][j] + qbk[r];
      logits[(size_t)r * S_LEN + scol] = val;
      float mx = val;
      mx = fmaxf(mx, __shfl_xor(mx, 1));
      mx = fmaxf(mx, __shfl_xor(mx, 2));
      mx = fmaxf(mx, __shfl_xor(mx, 4));
      mx = fmaxf(mx, __shfl_xor(mx, 8));
      if (l15 == 0) pmL[w * 64 + r] = mx;
    }
  }
  __syncthreads();
  if (t < 64) {
    float m0 = fmaxf(fmaxf(pmL[t], pmL[64 + t]), fmaxf(pmL[128 + t], pmL[192 + t]));
    pmax[(size_t)t * 1024 + wg] = m0;
  }
}

// E = exp(logits - gmax) bf16 + partial sums; gmax reduced per-block from pmax
__global__ void k_make_e(const float* __restrict__ logits, const float* __restrict__ pmax,
                         u16* __restrict__ E, float* __restrict__ plsum) {
  int b = blockIdx.x, t = threadIdx.x;     // 512 blocks
  int r = b >> 3, sc = b & 7;
  __shared__ float red[256];
  float mv = -3.0e38f;
#pragma unroll
  for (int i = 0; i < 4; ++i) mv = fmaxf(mv, pmax[(size_t)r * 1024 + t + i * 256]);
  red[t] = mv; __syncthreads();
  for (int s = 128; s > 0; s >>= 1) {
    if (t < s) red[t] = fmaxf(red[t], red[t + s]);
    __syncthreads();
  }
  float gm = red[0];
  __syncthreads();

  size_t base = (size_t)r * S_LEN + sc * 8192 + t * 32;
  const float* lp = logits + base;
  u16* ep = E + base;
  float sum = 0.f;
#pragma unroll
  for (int gi = 0; gi < 4; ++gi) {
    f32x4 f0 = *(const f32x4*)(lp + gi * 8);
    f32x4 f1 = *(const f32x4*)(lp + gi * 8 + 4);
    float e[8];
#pragma unroll
    for (int i = 0; i < 4; ++i) { e[i] = expf(f0[i] - gm); e[4 + i] = expf(f1[i] - gm); }
    union { uint4 u4; u16 s[8]; } pk;
#pragma unroll
    for (int i = 0; i < 8; ++i) { sum += e[i]; pk.s[i] = f2bf(e[i]); }
    *(uint4*)(ep + gi * 8) = pk.u4;
  }
  red[t] = sum; __syncthreads();
  for (int s = 128; s > 0; s >>= 1) {
    if (t < s) red[t] += red[t + s];
    __syncthreads();
  }
  if (t == 0) plsum[r * 8 + sc] = red[0];
}

// split-K: pew[chunk][64][1024] = E[:, chunk(1024 rows)] @ H[chunk, :]
__global__ __launch_bounds__(256) void k_pass2(
    const float* __restrict__ h, const u16* __restrict__ E, float* __restrict__ pew) {
  int t = threadIdx.x;
  int chunk = blockIdx.x >> 3, ctile = blockIdx.x & 7;   // 64 chunks x 8 ctiles
  int w = t >> 6, l = t & 63;
  int g = l >> 4, l15 = l & 15;
  int c0 = ctile * 128 + w * 32;
  f32x4 acc[4][2];
#pragma unroll
  for (int rb = 0; rb < 4; ++rb)
#pragma unroll
    for (int cb = 0; cb < 2; ++cb) acc[rb][cb] = (f32x4){0.f, 0.f, 0.f, 0.f};

  int kbase = chunk * 1024;
#pragma unroll 2
  for (int ks = 0; ks < 32; ++ks) {
    int k0 = kbase + ks * 32;
    bf16x8 af[4];
#pragma unroll
    for (int rb = 0; rb < 4; ++rb) {
      size_t eidx = (size_t)(rb * 16 + l15) * S_LEN + k0 + g * 8;
      uint4 u = *(const uint4*)(E + eidx);
      af[rb] = *(bf16x8*)&u;
    }
    bf16x8 bfb[2];
#pragma unroll
    for (int cb = 0; cb < 2; ++cb) {
      const float* hp = h + (size_t)(k0 + g * 8) * DM + c0 + cb * 16 + l15;
      float fb[8];
#pragma unroll
      for (int e = 0; e < 8; ++e) fb[e] = hp[(size_t)e * DM];
      bfb[cb] = pack_bf8(fb);
    }
#pragma unroll
    for (int rb = 0; rb < 4; ++rb)
#pragma unroll
      for (int cb = 0; cb < 2; ++cb)
        acc[rb][cb] = __builtin_amdgcn_mfma_f32_16x16x32_bf16(af[rb], bfb[cb], acc[rb][cb], 0, 0, 0);
  }
  float* pw = pew + (size_t)chunk * 65536;
#pragma unroll
  for (int rb = 0; rb < 4; ++rb)
#pragma unroll
    for (int cb = 0; cb < 2; ++cb)
#pragma unroll
      for (int j = 0; j < 4; ++j) {
        int r = rb * 16 + g * 4 + j;
        int c = c0 + cb * 16 + l15;
        pw[(size_t)r * 1024 + c] = acc[rb][cb][j];
      }
}

// reduce pew -> ewh (head-major), plus lsum
__global__ void k_red_ew(const float* __restrict__ pew, float* __restrict__ ewh,
                         const float* __restrict__ plsum, float* __restrict__ lsum) {
  int idx = blockIdx.x * 256 + threadIdx.x;   // 65536
  const float* p = pew + idx;
  float s = 0.f;
#pragma unroll 8
  for (int ch = 0; ch < 64; ++ch) s += p[(size_t)ch * 65536];
  int r = idx >> 10, c = idx & 1023;
  int m = r >> 3, hh = r & 7;
  ewh[hh * 8192 + c * 8 + m] = s;
  if (blockIdx.x == 0 && threadIdx.x < 64) {
    float lv = 0.f;
#pragma unroll
    for (int i = 0; i < 8; ++i) lv += plsum[threadIdx.x * 8 + i];
    lsum[threadIdx.x] = lv;
  }
}

__global__ void k_red_attn(const float* __restrict__ Pa, const float* __restrict__ lsum,
                           const float* __restrict__ bv, float* __restrict__ oatt) {
  int idx = blockIdx.x * 256 + threadIdx.x;   // 8192
  int m = idx >> 10, col = idx & 1023;
  int r = m * 8 + (col >> 7);
  float s = 0.f;
#pragma unroll 8
  for (int ks = 0; ks < 64; ++ks) s += Pa[(size_t)(ks * 8 + m) * 1024 + col];
  float lv = lsum[r];
  oatt[idx] = (s + lv * bv[col]) / (lv + 1e-9f);
}

// fused: reduce wo-partials -> o2, then LayerNorm -> xn. One block per m.
__global__ void k_red_o2_ln(const float* __restrict__ P, const float* __restrict__ bo,
                            const float* __restrict__ g, const float* __restrict__ b,
                            float* __restrict__ o2, float* __restrict__ xn) {
  int m = blockIdx.x, t = threadIdx.x;   // 8 x 256
  __shared__ float red[256], red2[256];
  f32x4 s4 = ((const f32x4*)bo)[t];
#pragma unroll 8
  for (int ks = 0; ks < 32; ++ks) {
    f32x4 p = ((const f32x4*)(P + (size_t)(ks * 8 + m) * 1024))[t];
#pragma unroll
    for (int j = 0; j < 4; ++j) s4[j] += p[j];
  }
  ((f32x4*)(o2 + m * 1024))[t] = s4;
  float s = s4[0] + s4[1] + s4[2] + s4[3];
  float s2 = s4[0]*s4[0] + s4[1]*s4[1] + s4[2]*s4[2] + s4[3]*s4[3];
  red[t] = s; red2[t] = s2; __syncthreads();
  for (int st = 128; st > 0; st >>= 1) {
    if (t < st) { red[t] += red[t + st]; red2[t] += red2[t + st]; }
    __syncthreads();
  }
  float mu = red[0] * (1.f / DM);
  float var = fmaxf(red2[0] * (1.f / DM) - mu * mu, 0.f);
  float rstd = rsqrtf(var + 1e-5f);
  f32x4 gg = ((const f32x4*)g)[t];
  f32x4 bb = ((const f32x4*)b)[t];
  f32x4 o;
#pragma unroll
  for (int j = 0; j < 4; ++j) o[j] = (s4[j] - mu) * rstd * gg[j] + bb[j];
  ((f32x4*)(xn + m * 1024))[t] = o;
}

__global__ void k_red_h1(const float* __restrict__ P, const float* __restrict__ b1,
                         float* __restrict__ h1) {
  int idx = blockIdx.x * 256 + threadIdx.x;   // 16384
  int m = idx >> 11, j = idx & 2047;
  float s = b1[j];
#pragma unroll 8
  for (int ks = 0; ks < 32; ++ks) s += P[(size_t)(ks * 8 + m) * 2048 + j];
  h1[idx] = 0.5f * s * (1.f + erff(s * 0.70710678118654752f));
}

// fused: reduce w2-partials + residual -> out, plus m_vec (mean over m)
__global__ void k_red_out_mvec(const float* __restrict__ P, const float* __restrict__ b2,
                               const float* __restrict__ o2, float* __restrict__ out) {
  int idx = blockIdx.x * 256 + threadIdx.x;   // 8192: j = idx>>3, m = idx&7
  int j = idx >> 3, m = idx & 7;
  float s = b2[j];
#pragma unroll 8
  for (int ks = 0; ks < 64; ++ks) s += P[(size_t)(ks * 8 + m) * 1024 + j];
  s += o2[m * 1024 + j];
  out[m * 1024 + j] = s;
  float sm = s;
  sm += __shfl_xor(sm, 1);
  sm += __shfl_xor(sm, 2);
  sm += __shfl_xor(sm, 4);
  if (m == 0) out[8192 + j] = sm * 0.125f;
}

extern "C" void kernel_launch(void* const* d_in, const int* in_sizes, int n_in,
                              void* d_out, int out_size, void* d_ws, size_t ws_size,
                              hipStream_t stream) {
  (void)in_sizes; (void)n_in; (void)out_size; (void)ws_size;
  const float* h   = (const float*)d_in[0];
  const float* lat = (const float*)d_in[1];
  const float* wq  = (const float*)d_in[2];
  const float* bq  = (const float*)d_in[3];
  const float* wk  = (const float*)d_in[4];
  const float* bk  = (const float*)d_in[5];
  const float* wv  = (const float*)d_in[6];
  const float* bv  = (const float*)d_in[7];
  const float* wo  = (const float*)d_in[8];
  const float* bo  = (const float*)d_in[9];
  const float* lng = (const float*)d_in[10];
  const float* lnb = (const float*)d_in[11];
  const float* w1  = (const float*)d_in[12];
  const float* b1  = (const float*)d_in[13];
  const float* w2  = (const float*)d_in[14];
  const float* b2  = (const float*)d_in[15];
  float* out = (float*)d_out;
  char* ws = (char*)d_ws;

  float* q      = (float*)(ws + WS_Q);
  u16*   qka    = (u16*)  (ws + WS_QKA);
  float* qbk    = (float*)(ws + WS_QBK);
  float* lsum   = (float*)(ws + WS_LSUM);
  float* plsum  = (float*)(ws + WS_PLSUM);
  float* xn     = (float*)(ws + WS_XN);
  float* ewh    = (float*)(ws + WS_EWH);
  float* pmax   = (float*)(ws + WS_PMAX);
  float* oatt   = (float*)(ws + WS_OATT);
  float* o2     = (float*)(ws + WS_O2);
  float* h1     = (float*)(ws + WS_H1);
  float* P      = (float*)(ws + WS_PBASE);
  float* logits = (float*)(ws + WS_LOGITS);
  float* pew    = (float*)(ws + WS_PEW);
  u16*   E      = (u16*)  (ws + WS_E);

  // ---- q = lat @ wq + bq (split-K) ----
  hipLaunchKernelGGL((k_sk8<32>), dim3(64),  dim3(256), 0, stream, lat, wq, P, 1024, 1024, 2);
  hipLaunchKernelGGL(k_red_q,     dim3(32),  dim3(256), 0, stream, P, bq, q);
  // ---- qkfold + qbk ----
  hipLaunchKernelGGL(k_foldqk,    dim3(128), dim3(256), 0, stream, q, wk, bk, qka, qbk);
  // ---- pass 1: logits + per-tile max ----
  hipLaunchKernelGGL(k_logits,    dim3(1024), dim3(256), 0, stream, h, qka, qbk, logits, pmax);
  hipLaunchKernelGGL(k_make_e,    dim3(512), dim3(256), 0, stream, logits, pmax, E, plsum);
  // ---- pass 2: EW partials + reduce ----
  hipLaunchKernelGGL(k_pass2,     dim3(512), dim3(256), 0, stream, h, E, pew);
  hipLaunchKernelGGL(k_red_ew,    dim3(256), dim3(256), 0, stream, pew, ewh, plsum, lsum);
  // ---- attention output ----
  hipLaunchKernelGGL(k_sk8h,      dim3(128), dim3(256), 0, stream, ewh, wv, P);
  hipLaunchKernelGGL(k_red_attn,  dim3(32),  dim3(256), 0, stream, P, lsum, bv, oatt);
  // ---- o2 = oatt @ wo + bo ; LN ----
  hipLaunchKernelGGL((k_sk8<32>), dim3(64),  dim3(256), 0, stream, oatt, wo, P, 1024, 1024, 2);
  hipLaunchKernelGGL(k_red_o2_ln, dim3(8),   dim3(256), 0, stream, P, bo, lng, lnb, o2, xn);
  // ---- MLP ----
  hipLaunchKernelGGL((k_sk8<32>), dim3(128), dim3(256), 0, stream, xn, w1, P, 2048, 1024, 4);
  hipLaunchKernelGGL(k_red_h1,    dim3(64),  dim3(256), 0, stream, P, b1, h1);
  hipLaunchKernelGGL((k_sk8<32>), dim3(128), dim3(256), 0, stream, h1, w2, P, 1024, 2048, 2);
  hipLaunchKernelGGL(k_red_out_mvec, dim3(32), dim3(256), 0, stream, P, b2, o2, out);
}